// Round 1
// baseline (24.834 us; speedup 1.0000x reference)
//
#include <hip/hip_runtime.h>

#define ROWS 128
#define COLS 128
#define NIMG 32
#define NG   128
#define PIX  (ROWS * COLS)

// out[n, r, c] = sum_g amp[n,g] * exp(-0.5*(a*dx^2 + b*dy^2 + 2*c*dx*dy))
//   where dx = lin[c] - cx[n,g], dy = lin[r] - cy[n,g], lin[i] = -1 + 2i/127.
// Params pre-scaled so inner loop uses exp2: a2=-0.5*log2e*a, b2=-0.5*log2e*b,
// c2=-log2e*c  =>  q2 = a2*dx^2 + b2*dy^2 + c2*dx*dy = log2( exp(-0.5 q) ).

__global__ __launch_bounds__(256) void rbf_kernel(
    const float* __restrict__ centers,      // (NIMG, NG, 2)
    const float* __restrict__ covs,         // (NIMG, NG, 3)
    const float* __restrict__ amps,         // (NIMG, NG, 1)
    float* __restrict__ out)                // (NIMG, ROWS, COLS)
{
    __shared__ float4 sp0[NG];  // (cx, cy, a2, c2)
    __shared__ float2 sp1[NG];  // (b2, amp)

    const int img  = blockIdx.x >> 6;        // 64 blocks of 256 px per image
    const int tile = blockIdx.x & 63;
    const int t    = threadIdx.x;

    if (t < NG) {
        const float LOG2E = 1.44269504088896340736f;
        int base = img * NG + t;
        float cx = centers[base * 2 + 0];
        float cy = centers[base * 2 + 1];
        float a  = covs[base * 3 + 0];
        float b  = covs[base * 3 + 1];
        float c  = covs[base * 3 + 2];
        float am = amps[base];
        sp0[t] = make_float4(cx, cy, -0.5f * LOG2E * a, -LOG2E * c);
        sp1[t] = make_float2(-0.5f * LOG2E * b, am);
    }
    __syncthreads();

    const int p = tile * 256 + t;            // p = r*COLS + c
    const int r = p >> 7;
    const int c = p & 127;
    const float step = 2.0f / 127.0f;
    const float xc = -1.0f + step * (float)c;   // dx uses lin[c]
    const float yr = -1.0f + step * (float)r;   // dy uses lin[r]

    float acc = 0.0f;
    #pragma unroll 8
    for (int g = 0; g < NG; ++g) {
        float4 p0 = sp0[g];
        float2 p1 = sp1[g];
        float dx = xc - p0.x;
        float dy = yr - p0.y;
        float t1 = p0.z * dx + p0.w * dy;    // a2*dx + c2*dy
        float t2 = p1.x * dy;                // b2*dy
        float q2 = t1 * dx + t2 * dy;        // -0.5*log2e*q
        acc += p1.y * __builtin_amdgcn_exp2f(q2);
    }

    out[img * PIX + p] = acc;
}

extern "C" void kernel_launch(void* const* d_in, const int* in_sizes, int n_in,
                              void* d_out, int out_size, void* d_ws, size_t ws_size,
                              hipStream_t stream) {
    const float* centers = (const float*)d_in[0];
    const float* covs    = (const float*)d_in[1];
    const float* amps    = (const float*)d_in[2];
    float* out           = (float*)d_out;

    dim3 grid(NIMG * (PIX / 256));   // 32 * 64 = 2048 blocks
    dim3 block(256);
    rbf_kernel<<<grid, block, 0, stream>>>(centers, covs, amps, out);
}